// Round 5
// baseline (343.509 us; speedup 1.0000x reference)
//
#include <hip/hip_runtime.h>
#include <math.h>

typedef unsigned short u16;
typedef unsigned int u32;
typedef __bf16 bf16x8 __attribute__((ext_vector_type(8)));
typedef float f32x4 __attribute__((ext_vector_type(4)));
typedef float f32x16 __attribute__((ext_vector_type(16)));
typedef u16 u16x4 __attribute__((ext_vector_type(4)));
typedef u16 u16x8 __attribute__((ext_vector_type(8)));
typedef u32 u32x4 __attribute__((ext_vector_type(4)));

#define MFMA16(a, b, c) __builtin_amdgcn_mfma_f32_16x16x32_bf16((a), (b), (c), 0, 0, 0)
#define MFMA32(a, b, c) __builtin_amdgcn_mfma_f32_32x32x16_bf16((a), (b), (c), 0, 0, 0)

#define GLL16(g, l)                                                   \
  __builtin_amdgcn_global_load_lds(                                   \
      (const __attribute__((address_space(1))) void*)(g),             \
      (__attribute__((address_space(3))) void*)(l), 16, 0, 0)

__device__ __forceinline__ u16 f2bf(float f) {
  __bf16 h = (__bf16)f;
  return __builtin_bit_cast(u16, h);
}
__device__ __forceinline__ u32 pack2(float a, float b) {
  return (u32)f2bf(a) | ((u32)f2bf(b) << 16);
}

// ---------------------------------------------------------------------------
// fp32 -> bf16 elementwise convert
// ---------------------------------------------------------------------------
__global__ __launch_bounds__(256) void cvt_f32_bf16(const float* __restrict__ in,
                                                    u16* __restrict__ out) {
  size_t i = ((size_t)blockIdx.x * 256 + threadIdx.x) * 4;
  float4 v = *(const float4*)(in + i);
  u16x4 o;
  o[0] = f2bf(v.x); o[1] = f2bf(v.y); o[2] = f2bf(v.z); o[3] = f2bf(v.w);
  *(u16x4*)(out + i) = o;
}

// ---------------------------------------------------------------------------
// fp32 in[R][Cn] -> bf16 out[Cn][R] (64x64 tiles, fused convert+transpose)
// ---------------------------------------------------------------------------
__global__ __launch_bounds__(256) void transpose_w(const float* __restrict__ in,
                                                   u16* __restrict__ out,
                                                   int R, int Cn) {
  __shared__ u16 tile[64][72];
  const int t = threadIdx.x;
  const int tr = blockIdx.y * 64;
  const int tc = blockIdx.x * 64;
#pragma unroll
  for (int p = 0; p < 4; ++p) {
    int chunk = p * 256 + t;
    int r = chunk >> 4, cq = chunk & 15;
    float4 v = *(const float4*)(in + (size_t)(tr + r) * Cn + tc + cq * 4);
    tile[r][cq * 4 + 0] = f2bf(v.x);
    tile[r][cq * 4 + 1] = f2bf(v.y);
    tile[r][cq * 4 + 2] = f2bf(v.z);
    tile[r][cq * 4 + 3] = f2bf(v.w);
  }
  __syncthreads();
#pragma unroll
  for (int p = 0; p < 2; ++p) {
    int chunk = p * 256 + t;
    int c = chunk >> 3, rg = chunk & 7;
    u16x8 v;
#pragma unroll
    for (int i = 0; i < 8; ++i) v[i] = tile[rg * 8 + i][c];
    *(u16x8*)(out + (size_t)(tc + c) * R + tr + rg * 8) = v;
  }
}

// ---------------------------------------------------------------------------
// V-part transpose (bf16 S): VT[(b*16+h)*64 + d][l] = S[b*2048+l][2048+h*64+d]
// ---------------------------------------------------------------------------
__global__ __launch_bounds__(256) void transpose_v(const u16* __restrict__ S,
                                                   u16* __restrict__ VT) {
  __shared__ u16 tile[64][72];
  const int t = threadIdx.x;
  const int lt = blockIdx.x;
  const int bh = blockIdx.y;
  const int b = bh >> 4, h = bh & 15;
  const u16* src = S + ((size_t)b * 2048 + (size_t)lt * 64) * 3072 + 2048 + h * 64;
  u16* dst = VT + (size_t)bh * 64 * 2048 + (size_t)lt * 64;
#pragma unroll
  for (int p = 0; p < 2; ++p) {
    int chunk = p * 256 + t;
    int r = chunk >> 3, cg = chunk & 7;
    u16x8 v = *(const u16x8*)(src + (size_t)r * 3072 + cg * 8);
    *(u16x8*)(&tile[r][cg * 8]) = v;
  }
  __syncthreads();
#pragma unroll
  for (int p = 0; p < 2; ++p) {
    int chunk = p * 256 + t;
    int d = chunk >> 3, rg = chunk & 7;
    u16x8 v;
#pragma unroll
    for (int i = 0; i < 8; ++i) v[i] = tile[rg * 8 + i][d];
    *(u16x8*)(dst + (size_t)d * 2048 + rg * 8) = v;
  }
}

// ---------------------------------------------------------------------------
// GEMM: C[M][N] = A[M][K] @ B, BT = B^T as [N][K]. 128x128 tile, BK=64.
// ---------------------------------------------------------------------------
template <bool OUTF32>
__global__ __launch_bounds__(256, 2) void gemm_bt(const u16* __restrict__ A,
                                                  const u16* __restrict__ BT,
                                                  void* __restrict__ Cp,
                                                  int M, int N, int K) {
  __shared__ u16 As[128 * 64];
  __shared__ u16 Bs[128 * 64];
  const int tid = threadIdx.x;
  const int lane = tid & 63;
  const int wid = tid >> 6;
  const int wr = wid >> 1, wc = wid & 1;
  const int rl = lane & 15, kg = lane >> 4;
  const size_t rowA0 = (size_t)blockIdx.y * 128;
  const size_t rowB0 = (size_t)blockIdx.x * 128;

  const int r_st = tid >> 3;
  const int cg_st = tid & 7;

  f32x4 acc[4][4] = {};

  for (int kb = 0; kb < K; kb += 64) {
    __syncthreads();
#pragma unroll
    for (int it = 0; it < 4; ++it) {
      int r = it * 32 + r_st;
      int cgs = cg_st ^ (r & 7);
      GLL16(A + (rowA0 + r) * K + kb + cgs * 8, As + (size_t)r * 64 + cg_st * 8);
      GLL16(BT + (rowB0 + r) * K + kb + cgs * 8, Bs + (size_t)r * 64 + cg_st * 8);
    }
    __syncthreads();

    bf16x8 af[2][4], bfr[2][4];
#pragma unroll
    for (int kk = 0; kk < 2; ++kk) {
      int c8 = kk * 4 + kg;
#pragma unroll
      for (int m = 0; m < 4; ++m) {
        int ra = wr * 64 + m * 16 + rl;
        af[kk][m] = *(const bf16x8*)(As + (size_t)ra * 64 + (size_t)((c8 ^ (ra & 7)) * 8));
        int rb = wc * 64 + m * 16 + rl;
        bfr[kk][m] = *(const bf16x8*)(Bs + (size_t)rb * 64 + (size_t)((c8 ^ (rb & 7)) * 8));
      }
    }
#pragma unroll
    for (int kk = 0; kk < 2; ++kk)
#pragma unroll
      for (int m = 0; m < 4; ++m)
#pragma unroll
        for (int n = 0; n < 4; ++n)
          acc[m][n] = MFMA16(af[kk][m], bfr[kk][n], acc[m][n]);
  }

#pragma unroll
  for (int m = 0; m < 4; ++m)
#pragma unroll
    for (int n = 0; n < 4; ++n)
#pragma unroll
      for (int j = 0; j < 4; ++j) {
        size_t r = rowA0 + wr * 64 + m * 16 + kg * 4 + j;
        size_t c = rowB0 + wc * 64 + n * 16 + rl;
        if constexpr (OUTF32)
          ((float*)Cp)[r * N + c] = acc[m][n][j];
        else
          ((u16*)Cp)[r * N + c] = f2bf(acc[m][n][j]);
      }
}

// ---------------------------------------------------------------------------
// Causal flash attention, swapped-operand 32x32x16 form.
// grid: x = g (16 pairs), y = bh (64). Block g owns q-64-tiles {g, 31-g};
// wave w: grp=w>>1 selects tile (g / 31-g), hw=w&1 selects 32-row half.
// Swapped QK^T (mfma(K,Q)) -> P^T[k=crow(r,hi)][q=ql] in-register;
// in-lane softmax; swapped PV (mfma(V^T,P^T)) keeps q on the lane axis.
//
// P^T B-frag per 16-k-step S=2*kb+s (derived & audited r4->r5):
//   regs 8s+j   of block kb hold k-offsets 4*hi+j    ("g0")
//   regs 8s+4+j of block kb hold k-offsets 8+4*hi+j  ("g1")
//   B-frag lane(hi) needs offsets 8*hi+i, i=0..7:
//     hi=0: own g0 (0..3)     ++ partner g0 (4..7)
//     hi=1: partner g1 (8..11) ++ own g1 (12..15)
//   -> send (hi ? g0 : g1) through shfl_xor(32), select.
// ---------------------------------------------------------------------------
__global__ __launch_bounds__(256) void attn(const u16* __restrict__ S,
                                            const u16* __restrict__ VT,
                                            u16* __restrict__ Y) {
  __shared__ u16 Ks[2][64 * 64];  // [krow][d], 16 KB
  __shared__ u16 Vs[2][64 * 64];  // [d][k]  (from VT), 16 KB
  const int g = blockIdx.x;       // 0..15
  const int t1 = 31 - g;
  const int bh = blockIdx.y;
  const int b = bh >> 4, h = bh & 15;
  const int tid = threadIdx.x, lane = tid & 63, wid = tid >> 6;
  const int ql = lane & 31;
  const int hi = lane >> 5;
  const int grp = wid >> 1;
  const int hw = wid & 1;
  const int myt = grp ? t1 : g;
  const int qrow = myt * 64 + hw * 32 + ql;

  const u16* Sq = S + (size_t)b * 2048 * 3072 + h * 64;
  const u16* Sk = Sq + 1024;
  const u16* Vh = VT + (size_t)bh * 64 * 2048;

  const int sr = tid >> 3, scg = tid & 7;

#define STAGE(buf, kt)                                                          \
  {                                                                             \
    _Pragma("unroll") for (int it = 0; it < 2; ++it) {                          \
      int r = it * 32 + sr;                                                     \
      int cs = scg ^ (r & 7); /* inverse-swizzled global source */              \
      GLL16(Sk + (size_t)((kt) * 64 + r) * 3072 + cs * 8,                       \
            &Ks[buf][r * 64 + scg * 8]);                                        \
      GLL16(Vh + (size_t)r * 2048 + (kt) * 64 + cs * 8,                         \
            &Vs[buf][r * 64 + scg * 8]);                                        \
    }                                                                           \
  }

  // Q B-frags (4 k-steps of 16 d), pre-scaled by 1/8 * log2(e)
  const float SC = 0.125f * 1.44269504088896f;
  bf16x8 qf[4];
#pragma unroll
  for (int s4 = 0; s4 < 4; ++s4) {
    bf16x8 q = *(const bf16x8*)(Sq + (size_t)qrow * 3072 + s4 * 16 + hi * 8);
    bf16x8 qs;
#pragma unroll
    for (int i = 0; i < 8; ++i) qs[i] = (__bf16)((float)q[i] * SC);
    qf[s4] = qs;
  }

  f32x16 O0 = {}, O1 = {};  // O^T: [d = db*32 + crow(r,hi)][q = ql]
  float mj = -INFINITY, lj = 0.f;

  STAGE(0, 0);
  __syncthreads();

  for (int kt = 0; kt <= t1; ++kt) {
    const int cur = kt & 1;
    if (kt < t1) STAGE(cur ^ 1, kt + 1);  // async prefetch over compute
    const u16* Ksb = Ks[cur];
    const u16* Vsb = Vs[cur];

    const bool active = (grp == 1) || (kt <= g);
    if (active) {
      // ---- swapped QK^T: P^T[k][q] ----
      f32x16 s0 = {}, s1 = {};
      __builtin_amdgcn_s_setprio(1);
#pragma unroll
      for (int s4 = 0; s4 < 4; ++s4) {
        int cix = (2 * s4 + hi) ^ (ql & 7);  // swizzled 16B chunk
        bf16x8 kf0 = *(const bf16x8*)(Ksb + (size_t)ql * 64 + cix * 8);
        bf16x8 kf1 = *(const bf16x8*)(Ksb + (size_t)(32 + ql) * 64 + cix * 8);
        s0 = MFMA32(kf0, qf[s4], s0);
        s1 = MFMA32(kf1, qf[s4], s1);
      }
      __builtin_amdgcn_s_setprio(0);

      // ---- diagonal mask (only on this wave's own diagonal tile) ----
      if (kt == myt) {
        const int lim = hw * 32 + ql;
#pragma unroll
        for (int r = 0; r < 16; ++r) {
          int c0 = (r & 3) + 8 * (r >> 2) + 4 * hi;  // crow
          s0[r] = (c0 <= lim) ? s0[r] : -INFINITY;
          s1[r] = (32 + c0 <= lim) ? s1[r] : -INFINITY;
        }
      }

      // ---- in-lane online softmax (base-2 domain) ----
      float t16[16];
#pragma unroll
      for (int r = 0; r < 16; ++r) t16[r] = fmaxf(s0[r], s1[r]);
#pragma unroll
      for (int off = 8; off >= 1; off >>= 1)
#pragma unroll
        for (int i = 0; i < 8; ++i)
          if (i < off) t16[i] = fmaxf(t16[i], t16[i + off]);
      float rmax = fmaxf(t16[0], __shfl_xor(t16[0], 32));
      float mn = fmaxf(mj, rmax);
      float scl = exp2f(mj - mn);  // 0 on first tile
      mj = mn;
#pragma unroll
      for (int r = 0; r < 16; ++r) {
        s0[r] = exp2f(s0[r] - mn);  // -inf -> 0
        s1[r] = exp2f(s1[r] - mn);
      }
      float a16[16];
#pragma unroll
      for (int r = 0; r < 16; ++r) a16[r] = s0[r] + s1[r];
#pragma unroll
      for (int off = 8; off >= 1; off >>= 1)
#pragma unroll
        for (int i = 0; i < 8; ++i)
          if (i < off) a16[i] += a16[i + off];
      float rsum = a16[0] + __shfl_xor(a16[0], 32);
      lj = lj * scl + rsum;
#pragma unroll
      for (int r = 0; r < 16; ++r) { O0[r] *= scl; O1[r] *= scl; }

      // ---- PV, swapped: O^T += V^T-frag x P^T-frag per 16-k-step ----
      __builtin_amdgcn_s_setprio(1);
#pragma unroll
      for (int Sstep = 0; Sstep < 4; ++Sstep) {
        const int kb = Sstep >> 1, s = Sstep & 1;
        // g0 = regs 8s+0..3, g1 = regs 8s+4..7 of block kb
        float e0 = kb ? s1[8 * s + 0] : s0[8 * s + 0];
        float e1 = kb ? s1[8 * s + 1] : s0[8 * s + 1];
        float e2 = kb ? s1[8 * s + 2] : s0[8 * s + 2];
        float e3 = kb ? s1[8 * s + 3] : s0[8 * s + 3];
        float f0 = kb ? s1[8 * s + 4] : s0[8 * s + 4];
        float f1 = kb ? s1[8 * s + 5] : s0[8 * s + 5];
        float f2 = kb ? s1[8 * s + 6] : s0[8 * s + 6];
        float f3 = kb ? s1[8 * s + 7] : s0[8 * s + 7];
        u32 a0 = pack2(e0, e1), a1 = pack2(e2, e3);  // g0: offsets 4*hi+0..3
        u32 b0 = pack2(f0, f1), b1 = pack2(f2, f3);  // g1: offsets 8+4*hi+0..3
        u32 s0w = hi ? a0 : b0;  // send what partner needs
        u32 s1w = hi ? a1 : b1;
        u32 r0 = (u32)__shfl_xor((int)s0w, 32);
        u32 r1 = (u32)__shfl_xor((int)s1w, 32);
        u32x4 pw;
        pw[0] = hi ? r0 : a0;  // offsets 8*hi + {0,1}
        pw[1] = hi ? r1 : a1;  //               {2,3}
        pw[2] = hi ? b0 : r0;  //               {4,5}
        pw[3] = hi ? b1 : r1;  //               {6,7}
        bf16x8 pf = __builtin_bit_cast(bf16x8, pw);
        int cix = (2 * Sstep + hi) ^ (ql & 7);
        bf16x8 vf0 = *(const bf16x8*)(Vsb + (size_t)ql * 64 + cix * 8);
        bf16x8 vf1 = *(const bf16x8*)(Vsb + (size_t)(32 + ql) * 64 + cix * 8);
        O0 = MFMA32(vf0, pf, O0);
        O1 = MFMA32(vf1, pf, O1);
      }
      __builtin_amdgcn_s_setprio(0);
    }
    __syncthreads();  // drain staged loads + protect buffer reuse
  }

  // ---- epilogue: O^T regs -> Y[qrow][h*64 + d] ----
  const float inv = 1.0f / lj;
  u16* yrow = Y + (size_t)(b * 2048 + qrow) * 1024 + h * 64;
#pragma unroll
  for (int db = 0; db < 2; ++db)
#pragma unroll
    for (int rq = 0; rq < 4; ++rq) {
      u16x4 o;
#pragma unroll
      for (int j = 0; j < 4; ++j) {
        float v = (db ? O1[rq * 4 + j] : O0[rq * 4 + j]) * inv;
        o[j] = f2bf(v);
      }
      *(u16x4*)(yrow + db * 32 + 8 * rq + 4 * hi) = o;
    }
#undef STAGE
}

// ---------------------------------------------------------------------------
extern "C" void kernel_launch(void* const* d_in, const int* in_sizes, int n_in,
                              void* d_out, int out_size, void* d_ws, size_t ws_size,
                              hipStream_t stream) {
  const float* x = (const float*)d_in[0];       // [8192][1024] fp32
  const float* w_attn = (const float*)d_in[1];  // [1024][3072] fp32
  const float* w_proj = (const float*)d_in[2];  // [1024][1024] fp32
  float* out = (float*)d_out;                   // [8192][1024] fp32

  u16* S = (u16*)d_ws;                          // 8192*3072 bf16
  u16* WT1 = S + (size_t)8192 * 3072;           // 3072*1024
  u16* WT2 = WT1 + (size_t)3072 * 1024;         // 1024*1024
  u16* VT = WT2 + (size_t)1024 * 1024;          // 64*64*2048
  u16* Y = VT + (size_t)64 * 64 * 2048;         // 8192*1024
  u16* XB = Y + (size_t)8192 * 1024;            // 8192*1024

  cvt_f32_bf16<<<8192, 256, 0, stream>>>(x, XB);
  transpose_w<<<dim3(3072 / 64, 1024 / 64), 256, 0, stream>>>(w_attn, WT1, 1024, 3072);
  transpose_w<<<dim3(1024 / 64, 1024 / 64), 256, 0, stream>>>(w_proj, WT2, 1024, 1024);
  gemm_bt<false><<<dim3(3072 / 128, 8192 / 128), 256, 0, stream>>>(XB, WT1, S, 8192, 3072, 1024);
  transpose_v<<<dim3(32, 64), 256, 0, stream>>>(S, VT);
  attn<<<dim3(16, 64), 256, 0, stream>>>(S, VT, Y);
  gemm_bt<true><<<dim3(1024 / 128, 8192 / 128), 256, 0, stream>>>(Y, WT2, out, 8192, 1024, 1024);
}

// Round 6
// 286.874 us; speedup vs baseline: 1.1974x; 1.1974x over previous
//
#include <hip/hip_runtime.h>
#include <math.h>

typedef unsigned short u16;
typedef unsigned int u32;
typedef __bf16 bf16x8 __attribute__((ext_vector_type(8)));
typedef float f32x4 __attribute__((ext_vector_type(4)));
typedef float f32x16 __attribute__((ext_vector_type(16)));
typedef u16 u16x4 __attribute__((ext_vector_type(4)));
typedef u16 u16x8 __attribute__((ext_vector_type(8)));
typedef u32 u32x4 __attribute__((ext_vector_type(4)));

#define MFMA16(a, b, c) __builtin_amdgcn_mfma_f32_16x16x32_bf16((a), (b), (c), 0, 0, 0)
#define MFMA32(a, b, c) __builtin_amdgcn_mfma_f32_32x32x16_bf16((a), (b), (c), 0, 0, 0)

#define GLL16(g, l)                                                   \
  __builtin_amdgcn_global_load_lds(                                   \
      (const __attribute__((address_space(1))) void*)(g),             \
      (__attribute__((address_space(3))) void*)(l), 16, 0, 0)

__device__ __forceinline__ u16 f2bf(float f) {
  __bf16 h = (__bf16)f;
  return __builtin_bit_cast(u16, h);
}
__device__ __forceinline__ u32 pack2(float a, float b) {
  return (u32)f2bf(a) | ((u32)f2bf(b) << 16);
}
// single-instruction 2^x (exp2f w/o fast-math is an OCML call sequence)
__device__ __forceinline__ float exp2a(float x) {
  float r;
  asm("v_exp_f32 %0, %1" : "=v"(r) : "v"(x));
  return r;
}

// ---------------------------------------------------------------------------
// fp32 -> bf16 elementwise convert
// ---------------------------------------------------------------------------
__global__ __launch_bounds__(256) void cvt_f32_bf16(const float* __restrict__ in,
                                                    u16* __restrict__ out) {
  size_t i = ((size_t)blockIdx.x * 256 + threadIdx.x) * 4;
  float4 v = *(const float4*)(in + i);
  u16x4 o;
  o[0] = f2bf(v.x); o[1] = f2bf(v.y); o[2] = f2bf(v.z); o[3] = f2bf(v.w);
  *(u16x4*)(out + i) = o;
}

// ---------------------------------------------------------------------------
// fp32 in[R][Cn] -> bf16 out[Cn][R] (64x64 tiles, fused convert+transpose)
// ---------------------------------------------------------------------------
__global__ __launch_bounds__(256) void transpose_w(const float* __restrict__ in,
                                                   u16* __restrict__ out,
                                                   int R, int Cn) {
  __shared__ u16 tile[64][72];
  const int t = threadIdx.x;
  const int tr = blockIdx.y * 64;
  const int tc = blockIdx.x * 64;
#pragma unroll
  for (int p = 0; p < 4; ++p) {
    int chunk = p * 256 + t;
    int r = chunk >> 4, cq = chunk & 15;
    float4 v = *(const float4*)(in + (size_t)(tr + r) * Cn + tc + cq * 4);
    tile[r][cq * 4 + 0] = f2bf(v.x);
    tile[r][cq * 4 + 1] = f2bf(v.y);
    tile[r][cq * 4 + 2] = f2bf(v.z);
    tile[r][cq * 4 + 3] = f2bf(v.w);
  }
  __syncthreads();
#pragma unroll
  for (int p = 0; p < 2; ++p) {
    int chunk = p * 256 + t;
    int c = chunk >> 3, rg = chunk & 7;
    u16x8 v;
#pragma unroll
    for (int i = 0; i < 8; ++i) v[i] = tile[rg * 8 + i][c];
    *(u16x8*)(out + (size_t)(tc + c) * R + tr + rg * 8) = v;
  }
}

// ---------------------------------------------------------------------------
// V-part transpose (bf16 S): VT[(b*16+h)*64 + d][l] = S[b*2048+l][2048+h*64+d]
// ---------------------------------------------------------------------------
__global__ __launch_bounds__(256) void transpose_v(const u16* __restrict__ S,
                                                   u16* __restrict__ VT) {
  __shared__ u16 tile[64][72];
  const int t = threadIdx.x;
  const int lt = blockIdx.x;
  const int bh = blockIdx.y;
  const int b = bh >> 4, h = bh & 15;
  const u16* src = S + ((size_t)b * 2048 + (size_t)lt * 64) * 3072 + 2048 + h * 64;
  u16* dst = VT + (size_t)bh * 64 * 2048 + (size_t)lt * 64;
#pragma unroll
  for (int p = 0; p < 2; ++p) {
    int chunk = p * 256 + t;
    int r = chunk >> 3, cg = chunk & 7;
    u16x8 v = *(const u16x8*)(src + (size_t)r * 3072 + cg * 8);
    *(u16x8*)(&tile[r][cg * 8]) = v;
  }
  __syncthreads();
#pragma unroll
  for (int p = 0; p < 2; ++p) {
    int chunk = p * 256 + t;
    int d = chunk >> 3, rg = chunk & 7;
    u16x8 v;
#pragma unroll
    for (int i = 0; i < 8; ++i) v[i] = tile[rg * 8 + i][d];
    *(u16x8*)(dst + (size_t)d * 2048 + rg * 8) = v;
  }
}

// ---------------------------------------------------------------------------
// GEMM: C[M][N] = A[M][K] @ B, BT = B^T as [N][K]. 128x128 tile, BK=64.
// XCD-aware block swizzle (nwg % 8 == 0 for all our launches).
// ---------------------------------------------------------------------------
template <bool OUTF32>
__global__ __launch_bounds__(256, 2) void gemm_bt(const u16* __restrict__ A,
                                                  const u16* __restrict__ BT,
                                                  void* __restrict__ Cp,
                                                  int M, int N, int K) {
  __shared__ u16 As[128 * 64];
  __shared__ u16 Bs[128 * 64];
  const int tid = threadIdx.x;
  const int lane = tid & 63;
  const int wid = tid >> 6;
  const int wr = wid >> 1, wc = wid & 1;
  const int rl = lane & 15, kg = lane >> 4;

  // XCD swizzle: consecutive dispatch ids (round-robin XCDs) -> contiguous
  // tile chunks per XCD (T1; bijective since nwg % 8 == 0).
  const int id = blockIdx.x + gridDim.x * blockIdx.y;
  const int cpx = (gridDim.x * gridDim.y) >> 3;
  const int swz = (id & 7) * cpx + (id >> 3);
  const int bx = swz % gridDim.x;
  const int by = swz / gridDim.x;
  const size_t rowA0 = (size_t)by * 128;
  const size_t rowB0 = (size_t)bx * 128;

  const int r_st = tid >> 3;
  const int cg_st = tid & 7;

  f32x4 acc[4][4] = {};

  for (int kb = 0; kb < K; kb += 64) {
    __syncthreads();
#pragma unroll
    for (int it = 0; it < 4; ++it) {
      int r = it * 32 + r_st;
      int cgs = cg_st ^ (r & 7);
      GLL16(A + (rowA0 + r) * K + kb + cgs * 8, As + (size_t)r * 64 + cg_st * 8);
      GLL16(BT + (rowB0 + r) * K + kb + cgs * 8, Bs + (size_t)r * 64 + cg_st * 8);
    }
    __syncthreads();

    bf16x8 af[2][4], bfr[2][4];
#pragma unroll
    for (int kk = 0; kk < 2; ++kk) {
      int c8 = kk * 4 + kg;
#pragma unroll
      for (int m = 0; m < 4; ++m) {
        int ra = wr * 64 + m * 16 + rl;
        af[kk][m] = *(const bf16x8*)(As + (size_t)ra * 64 + (size_t)((c8 ^ (ra & 7)) * 8));
        int rb = wc * 64 + m * 16 + rl;
        bfr[kk][m] = *(const bf16x8*)(Bs + (size_t)rb * 64 + (size_t)((c8 ^ (rb & 7)) * 8));
      }
    }
#pragma unroll
    for (int kk = 0; kk < 2; ++kk)
#pragma unroll
      for (int m = 0; m < 4; ++m)
#pragma unroll
        for (int n = 0; n < 4; ++n)
          acc[m][n] = MFMA16(af[kk][m], bfr[kk][n], acc[m][n]);
  }

#pragma unroll
  for (int m = 0; m < 4; ++m)
#pragma unroll
    for (int n = 0; n < 4; ++n)
#pragma unroll
      for (int j = 0; j < 4; ++j) {
        size_t r = rowA0 + wr * 64 + m * 16 + kg * 4 + j;
        size_t c = rowB0 + wc * 64 + n * 16 + rl;
        if constexpr (OUTF32)
          ((float*)Cp)[r * N + c] = acc[m][n][j];
        else
          ((u16*)Cp)[r * N + c] = f2bf(acc[m][n][j]);
      }
}

// ---------------------------------------------------------------------------
// Causal flash attention, swapped-operand 32x32x16 form.
// grid: x = bh (64), y = g (16)  -- all g-blocks of one bh land on ONE XCD
// (round-robin by linear id; 64 % 8 == 0), so the 512 KB K/V plane is
// L2-resident per XCD (8 planes = 4 MB = one XCD L2).
// T13 defer-max: rescale only when __any(rmax > mj + 8); P bounded by 2^8.
// exp2 via single v_exp_f32 (exp2a).
// ---------------------------------------------------------------------------
__global__ __launch_bounds__(256) void attn(const u16* __restrict__ S,
                                            const u16* __restrict__ VT,
                                            u16* __restrict__ Y) {
  __shared__ u16 Ks[2][64 * 64];  // [krow][d], 16 KB
  __shared__ u16 Vs[2][64 * 64];  // [d][k]  (from VT), 16 KB
  const int bh = blockIdx.x;
  const int g = blockIdx.y;       // 0..15
  const int t1 = 31 - g;
  const int b = bh >> 4, h = bh & 15;
  const int tid = threadIdx.x, lane = tid & 63, wid = tid >> 6;
  const int ql = lane & 31;
  const int hi = lane >> 5;
  const int grp = wid >> 1;
  const int hw = wid & 1;
  const int myt = grp ? t1 : g;
  const int qrow = myt * 64 + hw * 32 + ql;

  const u16* Sq = S + (size_t)b * 2048 * 3072 + h * 64;
  const u16* Sk = Sq + 1024;
  const u16* Vh = VT + (size_t)bh * 64 * 2048;

  const int sr = tid >> 3, scg = tid & 7;

#define STAGE(buf, kt)                                                          \
  {                                                                             \
    _Pragma("unroll") for (int it = 0; it < 2; ++it) {                          \
      int r = it * 32 + sr;                                                     \
      int cs = scg ^ (r & 7); /* inverse-swizzled global source */              \
      GLL16(Sk + (size_t)((kt) * 64 + r) * 3072 + cs * 8,                       \
            &Ks[buf][r * 64 + scg * 8]);                                        \
      GLL16(Vh + (size_t)r * 2048 + (kt) * 64 + cs * 8,                         \
            &Vs[buf][r * 64 + scg * 8]);                                        \
    }                                                                           \
  }

  // Q B-frags (4 k-steps of 16 d), pre-scaled by 1/8 * log2(e)
  const float SC = 0.125f * 1.44269504088896f;
  bf16x8 qf[4];
#pragma unroll
  for (int s4 = 0; s4 < 4; ++s4) {
    bf16x8 q = *(const bf16x8*)(Sq + (size_t)qrow * 3072 + s4 * 16 + hi * 8);
    bf16x8 qs;
#pragma unroll
    for (int i = 0; i < 8; ++i) qs[i] = (__bf16)((float)q[i] * SC);
    qf[s4] = qs;
  }

  f32x16 O0 = {}, O1 = {};  // O^T: [d = db*32 + crow(r,hi)][q = ql]
  float mj = -INFINITY, lj = 0.f;

  STAGE(0, 0);
  __syncthreads();

  for (int kt = 0; kt <= t1; ++kt) {
    const int cur = kt & 1;
    if (kt < t1) STAGE(cur ^ 1, kt + 1);  // async prefetch over compute
    const u16* Ksb = Ks[cur];
    const u16* Vsb = Vs[cur];

    const bool active = (grp == 1) || (kt <= g);
    if (active) {
      // ---- swapped QK^T: P^T[k][q] ----
      f32x16 s0 = {}, s1 = {};
      __builtin_amdgcn_s_setprio(1);
#pragma unroll
      for (int s4 = 0; s4 < 4; ++s4) {
        int cix = (2 * s4 + hi) ^ (ql & 7);  // swizzled 16B chunk
        bf16x8 kf0 = *(const bf16x8*)(Ksb + (size_t)ql * 64 + cix * 8);
        bf16x8 kf1 = *(const bf16x8*)(Ksb + (size_t)(32 + ql) * 64 + cix * 8);
        s0 = MFMA32(kf0, qf[s4], s0);
        s1 = MFMA32(kf1, qf[s4], s1);
      }
      __builtin_amdgcn_s_setprio(0);

      // ---- diagonal mask (only on this wave's own diagonal tile) ----
      if (kt == myt) {
        const int lim = hw * 32 + ql;
#pragma unroll
        for (int r = 0; r < 16; ++r) {
          int c0 = (r & 3) + 8 * (r >> 2) + 4 * hi;  // crow = k index
          s0[r] = (c0 <= lim) ? s0[r] : -INFINITY;
          s1[r] = (32 + c0 <= lim) ? s1[r] : -INFINITY;
        }
      }

      // ---- in-lane online softmax (base-2 domain) ----
      float t16[16];
#pragma unroll
      for (int r = 0; r < 16; ++r) t16[r] = fmaxf(s0[r], s1[r]);
#pragma unroll
      for (int off = 8; off >= 1; off >>= 1)
#pragma unroll
        for (int i = 0; i < 8; ++i)
          if (i < off) t16[i] = fmaxf(t16[i], t16[i + off]);
      // partner lane (xor 32) covers the other k-half of the SAME q row:
      // rmax is the full-row max (always finite -- diag row always present).
      float rmax = fmaxf(t16[0], __shfl_xor(t16[0], 32));

      // T13 defer-max: only rescale when the row max actually grew by > 8.
      if (__any(rmax > mj + 8.0f)) {
        float mn = (rmax > mj + 8.0f) ? rmax : mj;
        float scl = exp2a(mj - mn);  // 0 on first tile; 1 on !up lanes
        mj = mn;
        lj *= scl;
#pragma unroll
        for (int r = 0; r < 16; ++r) { O0[r] *= scl; O1[r] *= scl; }
      }

#pragma unroll
      for (int r = 0; r < 16; ++r) {
        s0[r] = exp2a(s0[r] - mj);  // -inf -> 0
        s1[r] = exp2a(s1[r] - mj);
      }
      float a16[16];
#pragma unroll
      for (int r = 0; r < 16; ++r) a16[r] = s0[r] + s1[r];
#pragma unroll
      for (int off = 8; off >= 1; off >>= 1)
#pragma unroll
        for (int i = 0; i < 8; ++i)
          if (i < off) a16[i] += a16[i + off];
      lj += a16[0] + __shfl_xor(a16[0], 32);

      // ---- PV, swapped: O^T += V^T-frag x P^T-frag per 16-k-step ----
      __builtin_amdgcn_s_setprio(1);
#pragma unroll
      for (int Sstep = 0; Sstep < 4; ++Sstep) {
        const int kb = Sstep >> 1, s = Sstep & 1;
        // g0 = regs 8s+0..3 (k = 4*hi+j), g1 = regs 8s+4..7 (k = 8+4*hi+j)
        float e0 = kb ? s1[8 * s + 0] : s0[8 * s + 0];
        float e1 = kb ? s1[8 * s + 1] : s0[8 * s + 1];
        float e2 = kb ? s1[8 * s + 2] : s0[8 * s + 2];
        float e3 = kb ? s1[8 * s + 3] : s0[8 * s + 3];
        float f0 = kb ? s1[8 * s + 4] : s0[8 * s + 4];
        float f1 = kb ? s1[8 * s + 5] : s0[8 * s + 5];
        float f2 = kb ? s1[8 * s + 6] : s0[8 * s + 6];
        float f3 = kb ? s1[8 * s + 7] : s0[8 * s + 7];
        u32 a0 = pack2(e0, e1), a1 = pack2(e2, e3);
        u32 b0 = pack2(f0, f1), b1 = pack2(f2, f3);
        u32 s0w = hi ? a0 : b0;  // send what partner needs
        u32 s1w = hi ? a1 : b1;
        u32 r0 = (u32)__shfl_xor((int)s0w, 32);
        u32 r1 = (u32)__shfl_xor((int)s1w, 32);
        u32x4 pw;
        pw[0] = hi ? r0 : a0;  // k offsets 8*hi + {0,1}
        pw[1] = hi ? r1 : a1;  //                {2,3}
        pw[2] = hi ? b0 : r0;  //                {4,5}
        pw[3] = hi ? b1 : r1;  //                {6,7}
        bf16x8 pf = __builtin_bit_cast(bf16x8, pw);
        int cix = (2 * Sstep + hi) ^ (ql & 7);
        bf16x8 vf0 = *(const bf16x8*)(Vsb + (size_t)ql * 64 + cix * 8);
        bf16x8 vf1 = *(const bf16x8*)(Vsb + (size_t)(32 + ql) * 64 + cix * 8);
        O0 = MFMA32(vf0, pf, O0);
        O1 = MFMA32(vf1, pf, O1);
      }
      __builtin_amdgcn_s_setprio(0);
    }
    __syncthreads();  // drain staged loads + protect buffer reuse
  }

  // ---- epilogue: O^T regs -> Y[qrow][h*64 + d] ----
  const float inv = 1.0f / lj;
  u16* yrow = Y + (size_t)(b * 2048 + qrow) * 1024 + h * 64;
#pragma unroll
  for (int db = 0; db < 2; ++db)
#pragma unroll
    for (int rq = 0; rq < 4; ++rq) {
      u16x4 o;
#pragma unroll
      for (int j = 0; j < 4; ++j) {
        float v = (db ? O1[rq * 4 + j] : O0[rq * 4 + j]) * inv;
        o[j] = f2bf(v);
      }
      *(u16x4*)(yrow + db * 32 + 8 * rq + 4 * hi) = o;
    }
#undef STAGE
}

// ---------------------------------------------------------------------------
extern "C" void kernel_launch(void* const* d_in, const int* in_sizes, int n_in,
                              void* d_out, int out_size, void* d_ws, size_t ws_size,
                              hipStream_t stream) {
  const float* x = (const float*)d_in[0];       // [8192][1024] fp32
  const float* w_attn = (const float*)d_in[1];  // [1024][3072] fp32
  const float* w_proj = (const float*)d_in[2];  // [1024][1024] fp32
  float* out = (float*)d_out;                   // [8192][1024] fp32

  u16* S = (u16*)d_ws;                          // 8192*3072 bf16
  u16* WT1 = S + (size_t)8192 * 3072;           // 3072*1024
  u16* WT2 = WT1 + (size_t)3072 * 1024;         // 1024*1024
  u16* VT = WT2 + (size_t)1024 * 1024;          // 64*64*2048
  u16* Y = VT + (size_t)64 * 64 * 2048;         // 8192*1024
  u16* XB = Y + (size_t)8192 * 1024;            // 8192*1024

  cvt_f32_bf16<<<8192, 256, 0, stream>>>(x, XB);
  transpose_w<<<dim3(3072 / 64, 1024 / 64), 256, 0, stream>>>(w_attn, WT1, 1024, 3072);
  transpose_w<<<dim3(1024 / 64, 1024 / 64), 256, 0, stream>>>(w_proj, WT2, 1024, 1024);
  gemm_bt<false><<<dim3(3072 / 128, 8192 / 128), 256, 0, stream>>>(XB, WT1, S, 8192, 3072, 1024);
  transpose_v<<<dim3(32, 64), 256, 0, stream>>>(S, VT);
  attn<<<dim3(64, 16), 256, 0, stream>>>(S, VT, Y);
  gemm_bt<true><<<dim3(1024 / 128, 8192 / 128), 256, 0, stream>>>(Y, WT2, out, 8192, 1024, 1024);
}